// Round 8
// baseline (245.176 us; speedup 1.0000x reference)
//
#include <hip/hip_runtime.h>
#include <hip/hip_bf16.h>

#define SEQ   4096
#define DIM   768
#define HEADS 12
#define NQKV  2304
// Q pre-scaled by 0.125*log2(e) in QKV epilogue -> p = 2^st = exp(score/8)
#define QSCALE 0.18033688011f

#if __has_builtin(__builtin_amdgcn_exp2f)
#define EXP2(x) __builtin_amdgcn_exp2f(x)
#else
#define EXP2(x) __expf((x) * 0.69314718056f)
#endif

typedef __bf16 bf16_t;
typedef bf16_t bf16x8 __attribute__((ext_vector_type(8)));
typedef float  f32x4  __attribute__((ext_vector_type(4)));
typedef float  f32x16 __attribute__((ext_vector_type(16)));
typedef unsigned short u16;
typedef unsigned int   u32;
typedef u16 u16x8 __attribute__((ext_vector_type(8)));

static __device__ __forceinline__ float bf2f(u16 v) {
    union { float f; unsigned u; } x; x.u = ((unsigned)v) << 16; return x.f;
}
static __device__ __forceinline__ u16 f2bf(float f) {
    union { float f; unsigned u; } x; x.f = f;
    unsigned r = x.u + 0x7fff + ((x.u >> 16) & 1);   // RNE
    return (u16)(r >> 16);
}
static __device__ __forceinline__ u32 fbits(float f) {
    union { float f; unsigned u; } x; x.f = f; return x.u;
}
static __device__ __forceinline__ float truncbf(float f) {
    union { unsigned u; float f; } x; x.u = fbits(f) & 0xFFFF0000u; return x.f;
}
static __device__ __forceinline__ void gload_lds16(const u16* g, u16* l) {
    __builtin_amdgcn_global_load_lds(
        (const __attribute__((address_space(1))) unsigned int*)g,
        (__attribute__((address_space(3))) unsigned int*)l, 16, 0, 0);
}

// per-block dtype self-detection (x fp32 vs bf16)
static __device__ __forceinline__ int detect_f32(const u32* __restrict__ x) {
    int lane = threadIdx.x & 63;
    int cnt = 0;
#pragma unroll
    for (int i = 0; i < 8; ++i) {
        u32 w = x[lane * 8 + i];
        cnt += (((w >> 7) & 0xFF) >= 0x8F) ? 1 : 0;
    }
#pragma unroll
    for (int m = 1; m < 64; m <<= 1) cnt += __shfl_xor(cnt, m);
    return cnt >= 64;
}

// ---- fused prep: [0,432) transpose w_qkv; [432,576) transpose w_proj; rest convert x+biases
__global__ __launch_bounds__(256) void prep(
    const void* __restrict__ x, const void* __restrict__ wqkv,
    const void* __restrict__ bqkv, const void* __restrict__ wproj,
    const void* __restrict__ bproj,
    u16* __restrict__ cvt, u16* __restrict__ wqkvT, u16* __restrict__ wprojT)
{
    __shared__ u16 tile[64][65];
    const bool f32 = detect_f32((const u32*)x) != 0;
    const int b = blockIdx.x;
    const int t = threadIdx.x;

    if (b < 576) {
        const void* src; u16* dst; int K, N, tx, ty;
        if (b < 432) { src = wqkv; dst = wqkvT; K = DIM; N = NQKV; tx = b % 36; ty = b / 36; }
        else { int bb = b - 432; src = wproj; dst = wprojT; K = DIM; N = DIM; tx = bb % 12; ty = bb / 12; }
        const int k0 = ty * 64, n0 = tx * 64;
#pragma unroll
        for (int i = 0; i < 16; ++i) {
            int idx = i * 256 + t;
            int r = idx >> 6, c = idx & 63;
            size_t si = (size_t)(k0 + r) * N + n0 + c;
            tile[r][c] = f32 ? f2bf(((const float*)src)[si]) : ((const u16*)src)[si];
        }
        __syncthreads();
#pragma unroll
        for (int i = 0; i < 16; ++i) {
            int idx = i * 256 + t;
            int r = idx >> 6, c = idx & 63;
            dst[(size_t)(n0 + r) * K + k0 + c] = tile[c][r];
        }
    } else {
        const int SX = SEQ * DIM, e1 = SX + NQKV;
        const int n_cvt = e1 + DIM;
        for (int i = (b - 576) * 256 + t; i < n_cvt; i += 200 * 256) {
            const void* s; int off;
            if      (i < SX) { s = x; off = i; }
            else if (i < e1) { s = bqkv; off = i - SX; }
            else             { s = bproj; off = i - e1; }
            cvt[i] = f32 ? f2bf(((const float*)s)[off]) : ((const u16*)s)[off];
        }
    }
}

// ---- m97-style GEMM: C[M,N] = A[M,K] @ BT[N,K]^T + bias[N]
// mode 0: out dtype per self-detect (fp32 Cf / bf16 C0).
// mode 1 (QKV): n<768 (Q) -> scaled by QSCALE; n<1536 (K) plain;
//   n>=1536 (V) -> VT[(n-1536)*SEQ + mp], mp = key with bits2,3 swapped per
//   16-group (matches attn PV sigma-permutation; P needs no C->A transform).
__global__ __launch_bounds__(256) void gemm128(
    const u16* __restrict__ A, const u16* __restrict__ BT, const u16* __restrict__ bias,
    u16* __restrict__ C0, float* __restrict__ Cf, u16* __restrict__ VT,
    const u32* __restrict__ xdet, int M, int N, int K, int mode)
{
    __shared__ u16 a_lds[128 * 32];
    __shared__ u16 b_lds[128 * 32];

    const int t    = threadIdx.x;
    const int w    = t >> 6;
    const int lane = t & 63;
    const int l15  = lane & 15;
    const int quad = lane >> 4;
    const int wm   = w >> 1, wn = w & 1;
    const int m0   = blockIdx.y * 128, n0 = blockIdx.x * 128;

    const int srow = w * 32 + (lane >> 2);
    const int kch  = (lane & 3) * 8;
    const u16* asrc = A  + (size_t)(m0 + srow) * K + kch;
    const u16* bsrc = BT + (size_t)(n0 + srow) * K + kch;
    u16* adst = a_lds + w * 32 * 32;
    u16* bdst = b_lds + w * 32 * 32;

    f32x4 acc[4][4] = {};

    for (int kt = 0; kt < K; kt += 32) {
        __syncthreads();
        gload_lds16(asrc,          adst);
        gload_lds16(asrc + 16 * K, adst + 16 * 32);
        gload_lds16(bsrc,          bdst);
        gload_lds16(bsrc + 16 * K, bdst + 16 * 32);
        asrc += 32; bsrc += 32;
        __syncthreads();

        const u16* ab = a_lds + (wm * 64 + l15) * 32 + quad * 8;
        const u16* bb = b_lds + (wn * 64 + l15) * 32 + quad * 8;
        bf16x8 af[4], bfr[4];
#pragma unroll
        for (int i = 0; i < 4; ++i) af[i]  = *(const bf16x8*)(ab + i * 16 * 32);
#pragma unroll
        for (int j = 0; j < 4; ++j) bfr[j] = *(const bf16x8*)(bb + j * 16 * 32);
#pragma unroll
        for (int i = 0; i < 4; ++i)
#pragma unroll
            for (int j = 0; j < 4; ++j)
                acc[i][j] = __builtin_amdgcn_mfma_f32_16x16x32_bf16(af[i], bfr[j], acc[i][j], 0, 0, 0);
    }

    const bool outf32 = (mode == 0) && detect_f32(xdet);
#pragma unroll
    for (int i = 0; i < 4; ++i)
#pragma unroll
        for (int j = 0; j < 4; ++j)
#pragma unroll
            for (int r = 0; r < 4; ++r) {
                int m = m0 + wm * 64 + i * 16 + quad * 4 + r;
                int n = n0 + wn * 64 + j * 16 + l15;
                float v = acc[i][j][r] + bf2f(bias[n]);
                if (mode == 0) {
                    if (outf32) Cf[(size_t)m * N + n] = v;
                    else        C0[(size_t)m * N + n] = f2bf(v);
                } else {
                    if (n < 768) {
                        C0[(size_t)m * 1536 + n] = f2bf(v * QSCALE);
                    } else if (n < 1536) {
                        C0[(size_t)m * 1536 + n] = f2bf(v);
                    } else {
                        int mp = (m & ~15) | (m & 3) |
                                 (((m >> 2) & 1) << 3) | (((m >> 3) & 1) << 2);
                        VT[(size_t)(n - 1536) * SEQ + mp] = f2bf(v);
                    }
                }
            }
}

// ---- Flash attention, 128-q blocks: every LDS fragment read feeds 2 MFMAs.
// Block = (128 q, head, key-part of 2048). 4 waves = (q-half wq: 64 q as two
// 32-q groups) x (key-half wk: 32 keys). S^T = K x Q^T; sigma-permuted V^T
// makes S^T C-regs directly the PV A-fragment. p = 2^st (Q pre-scaled).
// Row-sums via VALU on bf16-truncated p (consistent with PV operand).
// Double-buffered global_load_lds staging; outputs per-part O (bf16) + l (f32).
__global__ __launch_bounds__(256) void attn_kernel(
    const u16* __restrict__ qk, const u16* __restrict__ vt,
    u16* __restrict__ Opart, float* __restrict__ lpart)
{
    __shared__ u16 k_lds[2][64 * 64];
    __shared__ u16 v_lds[2][64 * 64];
    __shared__ float l_red[2][2][2][32];   // [wq][g][wk][q]

    const int t    = threadIdx.x;
    const int w    = t >> 6;
    const int lane = t & 63;
    const int l31  = lane & 31;
    const int h    = lane >> 5;
    const int wq   = w & 1;
    const int wk   = w >> 1;
    const int head = blockIdx.y;
    const int part = blockIdx.z;
    const int q0   = blockIdx.x * 128 + wq * 64;

    // Q B-frags for 2 q-groups: q = q0 + g*32 + l31, d = h*8 + 16s + j
    bf16x8 qb[2][4];
#pragma unroll
    for (int g = 0; g < 2; ++g) {
        const u16* qrow = qk + (size_t)(q0 + g * 32 + l31) * 1536 + head * 64 + h * 8;
#pragma unroll
        for (int s = 0; s < 4; ++s) qb[g][s] = *(const bf16x8*)(qrow + 16 * s);
    }

    // staging: lane -> row 8w+(lane>>3), stored chunk lane&7 = logical chunk cs
    const int srow = 8 * w + (lane >> 3);
    const int cs   = ((lane & 7) - srow) & 7;
    const u16* kg = qk + 768 + head * 64 + (size_t)(part * 2048 + srow) * 1536 + cs * 8;
    const u16* vg = vt + (size_t)head * 64 * SEQ + (size_t)srow * SEQ + part * 2048 + cs * 8;
    const int woff = 8 * w * 64;

    const int krow = 32 * wk + l31;

    f32x16 o0[2] = {}, o1[2] = {};
    float lsum[2] = {0.f, 0.f};

    auto stage = [&](u16* kd, u16* vd, int T) {
        const u16* kgT = kg + (size_t)T * 64 * 1536;
        const u16* vgT = vg + (size_t)T * 64;
        gload_lds16(kgT,                      kd + woff);
        gload_lds16(kgT + (size_t)32 * 1536,  kd + woff + 32 * 64);
        gload_lds16(vgT,                      vd + woff);
        gload_lds16(vgT + (size_t)32 * SEQ,   vd + woff + 32 * 64);
    };

    auto compute = [&](const u16* kb, const u16* vb) {
        f32x16 st0 = {}, st1 = {};
#pragma unroll
        for (int s = 0; s < 4; ++s) {
            bf16x8 ka = *(const bf16x8*)(kb + krow * 64 + (((2 * s + h + krow) & 7) * 8));
            st0 = __builtin_amdgcn_mfma_f32_32x32x16_bf16(ka, qb[0][s], st0, 0, 0, 0);
            st1 = __builtin_amdgcn_mfma_f32_32x32x16_bf16(ka, qb[1][s], st1, 0, 0, 0);
        }
        union { u32 u[4]; bf16x8 v; } pf[2][2];
#pragma unroll
        for (int g = 0; g < 2; ++g) {
            const f32x16& st = g ? st1 : st0;
#pragma unroll
            for (int i = 0; i < 8; ++i) {
                float pe = truncbf(EXP2(st[2 * i]));
                float po = truncbf(EXP2(st[2 * i + 1]));
                lsum[g] += pe + po;
                pf[g][i >> 2].u[i & 3] =
                    __builtin_amdgcn_perm(fbits(po), fbits(pe), 0x07060302u);
            }
        }
#pragma unroll
        for (int s2 = 0; s2 < 2; ++s2) {
            const int c = 4 * wk + 2 * s2 + h;
            bf16x8 vb0 = *(const bf16x8*)(vb + l31 * 64 + (((c + l31) & 7) * 8));
            bf16x8 vb1 = *(const bf16x8*)(vb + (32 + l31) * 64 + (((c + 32 + l31) & 7) * 8));
#pragma unroll
            for (int g = 0; g < 2; ++g) {
                o0[g] = __builtin_amdgcn_mfma_f32_32x32x16_bf16(pf[g][s2].v, vb0, o0[g], 0, 0, 0);
                o1[g] = __builtin_amdgcn_mfma_f32_32x32x16_bf16(pf[g][s2].v, vb1, o1[g], 0, 0, 0);
            }
        }
    };

    stage(&k_lds[0][0], &v_lds[0][0], 0);
    __syncthreads();
    for (int T = 0; T < 32; T += 2) {
        stage(&k_lds[1][0], &v_lds[1][0], T + 1);
        compute(&k_lds[0][0], &v_lds[0][0]);
        __syncthreads();
        if (T + 2 < 32) stage(&k_lds[0][0], &v_lds[0][0], T + 2);
        compute(&k_lds[1][0], &v_lds[1][0]);
        __syncthreads();
    }

    // l: combine h-halves, publish per q
#pragma unroll
    for (int g = 0; g < 2; ++g) {
        lsum[g] += __shfl_xor(lsum[g], 32);
        if (h == 0) l_red[wq][g][wk][l31] = lsum[g];
    }
    // O cross-wk reduce: scratch = this q-half's 16 KB (qh0 -> k_lds, qh1 -> v_lds)
    float* scr = (wq == 0) ? (float*)&k_lds[0][0] : (float*)&v_lds[0][0];
    if (wk == 1) {
#pragma unroll
        for (int g = 0; g < 2; ++g)
#pragma unroll
            for (int r = 0; r < 16; ++r) {
                int row = g * 32 + (r & 3) + 8 * (r >> 2) + 4 * h;
                scr[row * 64 + l31]      = o0[g][r];
                scr[row * 64 + 32 + l31] = o1[g][r];
            }
    }
    __syncthreads();
    if (wk == 0) {
        const size_t pb = (size_t)(part * HEADS + head) * SEQ;
#pragma unroll
        for (int g = 0; g < 2; ++g)
#pragma unroll
            for (int r = 0; r < 16; ++r) {
                int row = (r & 3) + 8 * (r >> 2) + 4 * h;
                int qrow_ = q0 + g * 32 + row;
                float lt = l_red[wq][g][0][row] + l_red[wq][g][1][row];
                float s0 = o0[g][r] + scr[(g * 32 + row) * 64 + l31];
                float s1 = o1[g][r] + scr[(g * 32 + row) * 64 + 32 + l31];
                size_t ob = (pb + qrow_) * 64;
                Opart[ob + l31]      = f2bf(s0);
                Opart[ob + 32 + l31] = f2bf(s1);
                if (l31 == 0) lpart[pb + qrow_] = lt;
            }
    }
}

// ---- combine the two key-part partials -> attnb [q][h*64+d] bf16
__global__ __launch_bounds__(256) void combine(
    const u16* __restrict__ Opart, const float* __restrict__ lpart,
    u16* __restrict__ outb)
{
    const int PSTR = HEADS * SEQ * 64;
    const int LSTR = HEADS * SEQ;
    int idx = (blockIdx.x * 256 + threadIdx.x) * 8;   // over [h][q][d]
    int hq  = idx >> 6;
    int d0  = idx & 63;
    float invl = 1.0f / (lpart[hq] + lpart[LSTR + hq]);
    u16x8 a = *(const u16x8*)(Opart + idx);
    u16x8 b = *(const u16x8*)(Opart + PSTR + idx);
    int h = hq >> 12, q = hq & 4095;
    u16x8 o;
#pragma unroll
    for (int i = 0; i < 8; ++i)
        o[i] = f2bf((bf2f(a[i]) + bf2f(b[i])) * invl);
    *(u16x8*)(outb + (size_t)q * 768 + h * 64 + d0) = o;
}

extern "C" void kernel_launch(void* const* d_in, const int* in_sizes, int n_in,
                              void* d_out, int out_size, void* d_ws, size_t ws_size,
                              hipStream_t stream) {
    const int SX = SEQ * DIM;

    u16* base   = (u16*)d_ws;
    u16* xb     = base;                               // [SEQ][DIM] bf16
    u16* bqkvb  = xb + SX;
    u16* bprojb = bqkvb + NQKV;
    u16* wqkvT  = bprojb + DIM;                       // [NQKV][DIM]
    u16* wprojT = wqkvT + (size_t)NQKV * DIM;         // [DIM][DIM]
    u16* qkb    = wprojT + (size_t)DIM * DIM;         // [SEQ][1536] Q(scaled)|K
    u16* vtb    = qkb + (size_t)SEQ * 1536;           // [H][64][SEQ] V^T (sigma keys)
    u16* opart  = vtb + (size_t)HEADS * 64 * SEQ;     // [2][H][SEQ][64] bf16
    float* lpart= (float*)(opart + (size_t)2 * HEADS * SEQ * 64);  // [2][H][SEQ]
    u16* attnb  = xb;                                 // reuse x region

    prep<<<776, 256, 0, stream>>>(
        d_in[0], d_in[1], d_in[2], d_in[3], d_in[4], base, wqkvT, wprojT);
    gemm128<<<dim3(NQKV / 128, SEQ / 128), 256, 0, stream>>>(
        xb, wqkvT, bqkvb, qkb, nullptr, vtb, (const u32*)d_in[0],
        SEQ, NQKV, DIM, 1);
    attn_kernel<<<dim3(SEQ / 128, HEADS, 2), 256, 0, stream>>>(qkb, vtb, opart, lpart);
    combine<<<(HEADS * SEQ * 64) / (256 * 8), 256, 0, stream>>>(opart, lpart, attnb);
    gemm128<<<dim3(DIM / 128, SEQ / 128), 256, 0, stream>>>(
        attnb, wprojT, bprojb, (u16*)d_out, (float*)d_out, nullptr,
        (const u32*)d_in[0], SEQ, DIM, DIM, 0);
}

// Round 9
// 231.612 us; speedup vs baseline: 1.0586x; 1.0586x over previous
//
#include <hip/hip_runtime.h>
#include <hip/hip_bf16.h>

#define SEQ   4096
#define DIM   768
#define HEADS 12
#define NQKV  2304
// Q pre-scaled by 0.125*log2(e) in QKV epilogue -> p = 2^st = exp(score/8)
#define QSCALE 0.18033688011f

#if __has_builtin(__builtin_amdgcn_exp2f)
#define EXP2(x) __builtin_amdgcn_exp2f(x)
#else
#define EXP2(x) __expf((x) * 0.69314718056f)
#endif

typedef __bf16 bf16_t;
typedef bf16_t bf16x8 __attribute__((ext_vector_type(8)));
typedef float  f32x4  __attribute__((ext_vector_type(4)));
typedef float  f32x16 __attribute__((ext_vector_type(16)));
typedef unsigned short u16;
typedef unsigned int   u32;

static __device__ __forceinline__ float bf2f(u16 v) {
    union { float f; unsigned u; } x; x.u = ((unsigned)v) << 16; return x.f;
}
static __device__ __forceinline__ u16 f2bf(float f) {
    union { float f; unsigned u; } x; x.f = f;
    unsigned r = x.u + 0x7fff + ((x.u >> 16) & 1);   // RNE
    return (u16)(r >> 16);
}
static __device__ __forceinline__ u32 fbits(float f) {
    union { float f; unsigned u; } x; x.f = f; return x.u;
}
static __device__ __forceinline__ void gload_lds16(const u16* g, u16* l) {
    __builtin_amdgcn_global_load_lds(
        (const __attribute__((address_space(1))) unsigned int*)g,
        (__attribute__((address_space(3))) unsigned int*)l, 16, 0, 0);
}

// per-block dtype self-detection (x fp32 vs bf16)
static __device__ __forceinline__ int detect_f32(const u32* __restrict__ x) {
    int lane = threadIdx.x & 63;
    int cnt = 0;
#pragma unroll
    for (int i = 0; i < 8; ++i) {
        u32 w = x[lane * 8 + i];
        cnt += (((w >> 7) & 0xFF) >= 0x8F) ? 1 : 0;
    }
#pragma unroll
    for (int m = 1; m < 64; m <<= 1) cnt += __shfl_xor(cnt, m);
    return cnt >= 64;
}

// ---- fused prep: [0,432) transpose w_qkv; [432,576) transpose w_proj; rest convert x+biases
__global__ __launch_bounds__(256) void prep(
    const void* __restrict__ x, const void* __restrict__ wqkv,
    const void* __restrict__ bqkv, const void* __restrict__ wproj,
    const void* __restrict__ bproj,
    u16* __restrict__ cvt, u16* __restrict__ wqkvT, u16* __restrict__ wprojT)
{
    __shared__ u16 tile[64][65];
    const bool f32 = detect_f32((const u32*)x) != 0;
    const int b = blockIdx.x;
    const int t = threadIdx.x;

    if (b < 576) {
        const void* src; u16* dst; int K, N, tx, ty;
        if (b < 432) { src = wqkv; dst = wqkvT; K = DIM; N = NQKV; tx = b % 36; ty = b / 36; }
        else { int bb = b - 432; src = wproj; dst = wprojT; K = DIM; N = DIM; tx = bb % 12; ty = bb / 12; }
        const int k0 = ty * 64, n0 = tx * 64;
#pragma unroll
        for (int i = 0; i < 16; ++i) {
            int idx = i * 256 + t;
            int r = idx >> 6, c = idx & 63;
            size_t si = (size_t)(k0 + r) * N + n0 + c;
            tile[r][c] = f32 ? f2bf(((const float*)src)[si]) : ((const u16*)src)[si];
        }
        __syncthreads();
#pragma unroll
        for (int i = 0; i < 16; ++i) {
            int idx = i * 256 + t;
            int r = idx >> 6, c = idx & 63;
            dst[(size_t)(n0 + r) * K + k0 + c] = tile[c][r];
        }
    } else {
        const int SX = SEQ * DIM, e1 = SX + NQKV;
        const int n_cvt = e1 + DIM;
        for (int i = (b - 576) * 256 + t; i < n_cvt; i += 200 * 256) {
            const void* s; int off;
            if      (i < SX) { s = x; off = i; }
            else if (i < e1) { s = bqkv; off = i - SX; }
            else             { s = bproj; off = i - e1; }
            cvt[i] = f32 ? f2bf(((const float*)s)[off]) : ((const u16*)s)[off];
        }
    }
}

// ---- m97-style GEMM: C[M,N] = A[M,K] @ BT[N,K]^T + bias[N]
// MODE 0: out dtype per self-detect (fp32 Cf / bf16 C0).
// MODE 1 (QKV): n<768 (Q) -> scaled by QSCALE; n<1536 (K) plain;
//   n>=1536 (V) -> VT[(n-1536)*SEQ + mp], mp = key with bits2,3 swapped per
//   16-group (matches attn PV sigma-permutation; P needs no C->A transform).
template<int MODE>
__global__ __launch_bounds__(256) void gemm128(
    const u16* __restrict__ A, const u16* __restrict__ BT, const u16* __restrict__ bias,
    u16* __restrict__ C0, float* __restrict__ Cf, u16* __restrict__ VT,
    const u32* __restrict__ xdet, int M, int N, int K)
{
    __shared__ u16 a_lds[128 * 32];
    __shared__ u16 b_lds[128 * 32];

    const int t    = threadIdx.x;
    const int w    = t >> 6;
    const int lane = t & 63;
    const int l15  = lane & 15;
    const int quad = lane >> 4;
    const int wm   = w >> 1, wn = w & 1;
    const int m0   = blockIdx.y * 128, n0 = blockIdx.x * 128;

    const int srow = w * 32 + (lane >> 2);
    const int kch  = (lane & 3) * 8;
    const u16* asrc = A  + (size_t)(m0 + srow) * K + kch;
    const u16* bsrc = BT + (size_t)(n0 + srow) * K + kch;
    u16* adst = a_lds + w * 32 * 32;
    u16* bdst = b_lds + w * 32 * 32;

    f32x4 acc[4][4] = {};

    for (int kt = 0; kt < K; kt += 32) {
        __syncthreads();
        gload_lds16(asrc,          adst);
        gload_lds16(asrc + 16 * K, adst + 16 * 32);
        gload_lds16(bsrc,          bdst);
        gload_lds16(bsrc + 16 * K, bdst + 16 * 32);
        asrc += 32; bsrc += 32;
        __syncthreads();

        const u16* ab = a_lds + (wm * 64 + l15) * 32 + quad * 8;
        const u16* bb = b_lds + (wn * 64 + l15) * 32 + quad * 8;
        bf16x8 af[4], bfr[4];
#pragma unroll
        for (int i = 0; i < 4; ++i) af[i]  = *(const bf16x8*)(ab + i * 16 * 32);
#pragma unroll
        for (int j = 0; j < 4; ++j) bfr[j] = *(const bf16x8*)(bb + j * 16 * 32);
#pragma unroll
        for (int i = 0; i < 4; ++i)
#pragma unroll
            for (int j = 0; j < 4; ++j)
                acc[i][j] = __builtin_amdgcn_mfma_f32_16x16x32_bf16(af[i], bfr[j], acc[i][j], 0, 0, 0);
    }

    bool outf32 = false;
    if (MODE == 0) outf32 = detect_f32(xdet) != 0;
#pragma unroll
    for (int i = 0; i < 4; ++i)
#pragma unroll
        for (int j = 0; j < 4; ++j)
#pragma unroll
            for (int r = 0; r < 4; ++r) {
                int m = m0 + wm * 64 + i * 16 + quad * 4 + r;
                int n = n0 + wn * 64 + j * 16 + l15;
                float v = acc[i][j][r] + bf2f(bias[n]);
                if (MODE == 0) {
                    if (outf32) Cf[(size_t)m * N + n] = v;
                    else        C0[(size_t)m * N + n] = f2bf(v);
                } else {
                    if (n < 768) {
                        C0[(size_t)m * 1536 + n] = f2bf(v * QSCALE);
                    } else if (n < 1536) {
                        C0[(size_t)m * 1536 + n] = f2bf(v);
                    } else {
                        int mp = (m & ~15) | (m & 3) |
                                 (((m >> 2) & 1) << 3) | (((m >> 3) & 1) << 2);
                        VT[(size_t)(n - 1536) * SEQ + mp] = f2bf(v);
                    }
                }
            }
}

// ---- Flash attention (R6 structure + VALU diet). Block = (64 q, head).
// 4 waves = (q-half wq) x (key-half wk). S^T = K x Q^T; sigma-permuted V^T
// makes S^T C-regs directly the PV A-fragment. p = 2^st (Q pre-scaled by
// QSCALE). Row-sums via ones-MFMA on the SAME packed/truncated P fragment
// (consistent normalization). Double-buffered global_load_lds staging.
__global__ __launch_bounds__(256) void attn_kernel(
    const u16* __restrict__ qk, const u16* __restrict__ vt, u16* __restrict__ out)
{
    __shared__ u16 k_lds[2][64 * 64];
    __shared__ u16 v_lds[2][64 * 64];
    __shared__ float l_red[2][2][32];   // [wq][wk][q]

    const int t    = threadIdx.x;
    const int w    = t >> 6;
    const int lane = t & 63;
    const int l31  = lane & 31;
    const int h    = lane >> 5;
    const int wq   = w & 1;
    const int wk   = w >> 1;
    const int head = blockIdx.y;
    const int q0   = blockIdx.x * 64 + wq * 32;

    // Q B-frags: q = q0+l31, d = h*8+16s+j (Q pre-scaled by QSCALE)
    const u16* qrow = qk + (size_t)(q0 + l31) * 1536 + head * 64 + h * 8;
    bf16x8 qb[4];
#pragma unroll
    for (int s = 0; s < 4; ++s) qb[s] = *(const bf16x8*)(qrow + 16 * s);

    bf16x8 ones;
#pragma unroll
    for (int j = 0; j < 8; ++j) ones[j] = (bf16_t)1.0f;

    // staging: lane -> row 8w+(lane>>3), stored chunk lane&7 = logical chunk cs
    const int srow = 8 * w + (lane >> 3);
    const int cs   = ((lane & 7) - srow) & 7;
    const u16* kg = qk + 768 + head * 64 + (size_t)srow * 1536 + cs * 8;
    const u16* vg = vt + (size_t)head * 64 * SEQ + (size_t)srow * SEQ + cs * 8;
    const int woff = 8 * w * 64;

    const int krow = 32 * wk + l31;

    f32x16 o0 = {}, o1 = {}, lac = {};

    auto stage = [&](u16* kd, u16* vd, int T) {
        const u16* kgT = kg + (size_t)T * 64 * 1536;
        const u16* vgT = vg + (size_t)T * 64;
        gload_lds16(kgT,                      kd + woff);
        gload_lds16(kgT + (size_t)32 * 1536,  kd + woff + 32 * 64);
        gload_lds16(vgT,                      vd + woff);
        gload_lds16(vgT + (size_t)32 * SEQ,   vd + woff + 32 * 64);
    };

    auto compute = [&](const u16* kb, const u16* vb) {
        f32x16 st = {};
#pragma unroll
        for (int s = 0; s < 4; ++s) {
            bf16x8 ka = *(const bf16x8*)(kb + krow * 64 + (((2 * s + h + krow) & 7) * 8));
            st = __builtin_amdgcn_mfma_f32_32x32x16_bf16(ka, qb[s], st, 0, 0, 0);
        }
        u32 q32[8];
#pragma unroll
        for (int i = 0; i < 8; ++i) {
            float pe = EXP2(st[2 * i]);
            float po = EXP2(st[2 * i + 1]);
            q32[i] = __builtin_amdgcn_perm(fbits(po), fbits(pe), 0x07060302u);
        }
        union { u32 u[4]; bf16x8 v; } pf0, pf1;
#pragma unroll
        for (int i = 0; i < 4; ++i) { pf0.u[i] = q32[i]; pf1.u[i] = q32[4 + i]; }
#pragma unroll
        for (int s2 = 0; s2 < 2; ++s2) {
            const int c = 4 * wk + 2 * s2 + h;
            bf16x8 vb0 = *(const bf16x8*)(vb + l31 * 64 + (((c + l31) & 7) * 8));
            bf16x8 vb1 = *(const bf16x8*)(vb + (32 + l31) * 64 + (((c + 32 + l31) & 7) * 8));
            const bf16x8 pv = s2 ? pf1.v : pf0.v;
            o0  = __builtin_amdgcn_mfma_f32_32x32x16_bf16(pv, vb0, o0, 0, 0, 0);
            o1  = __builtin_amdgcn_mfma_f32_32x32x16_bf16(pv, vb1, o1, 0, 0, 0);
            lac = __builtin_amdgcn_mfma_f32_32x32x16_bf16(pv, ones, lac, 0, 0, 0);
        }
    };

    stage(&k_lds[0][0], &v_lds[0][0], 0);
    __syncthreads();
    for (int T = 0; T < 64; T += 2) {
        stage(&k_lds[1][0], &v_lds[1][0], T + 1);
        compute(&k_lds[0][0], &v_lds[0][0]);
        __syncthreads();
        if (T + 2 < 64) stage(&k_lds[0][0], &v_lds[0][0], T + 2);
        compute(&k_lds[1][0], &v_lds[1][0]);
        __syncthreads();
    }

    // publish l per q-row (lac is lane-uniform along cols: col=n of ones)
    if (l31 == 0) {
#pragma unroll
        for (int r = 0; r < 16; ++r) {
            int row = (r & 3) + 8 * (r >> 2) + 4 * h;
            l_red[wq][wk][row] = lac[r];
        }
    }
    // O cross-wk reduce via LDS scratch (qh0 -> k_lds, qh1 -> v_lds)
    float* scr = (wq == 0) ? (float*)&k_lds[0][0] : (float*)&v_lds[0][0];
    if (wk == 1) {
#pragma unroll
        for (int r = 0; r < 16; ++r) {
            int row = (r & 3) + 8 * (r >> 2) + 4 * h;
            scr[row * 64 + l31]      = o0[r];
            scr[row * 64 + 32 + l31] = o1[r];
        }
    }
    __syncthreads();
    if (wk == 0) {
#pragma unroll
        for (int r = 0; r < 16; ++r) {
            int row = (r & 3) + 8 * (r >> 2) + 4 * h;
            float lt   = l_red[wq][0][row] + l_red[wq][1][row];
            float invl = 1.0f / lt;
            float s0 = o0[r] + scr[row * 64 + l31];
            float s1 = o1[r] + scr[row * 64 + 32 + l31];
            size_t gr = (size_t)(q0 + row) * 768 + head * 64;
            out[gr + l31]      = f2bf(s0 * invl);
            out[gr + 32 + l31] = f2bf(s1 * invl);
        }
    }
}

extern "C" void kernel_launch(void* const* d_in, const int* in_sizes, int n_in,
                              void* d_out, int out_size, void* d_ws, size_t ws_size,
                              hipStream_t stream) {
    const int SX = SEQ * DIM;

    u16* base   = (u16*)d_ws;
    u16* xb     = base;                               // [SEQ][DIM] bf16
    u16* bqkvb  = xb + SX;
    u16* bprojb = bqkvb + NQKV;
    u16* wqkvT  = bprojb + DIM;                       // [NQKV][DIM]
    u16* wprojT = wqkvT + (size_t)NQKV * DIM;         // [DIM][DIM]
    u16* qkb    = wprojT + (size_t)DIM * DIM;         // [SEQ][1536] Q(scaled)|K
    u16* vtb    = qkb + (size_t)SEQ * 1536;           // [H][64][SEQ] V^T (sigma keys)
    u16* attnb  = xb;                                 // reuse x region

    prep<<<776, 256, 0, stream>>>(
        d_in[0], d_in[1], d_in[2], d_in[3], d_in[4], base, wqkvT, wprojT);
    gemm128<1><<<dim3(NQKV / 128, SEQ / 128), 256, 0, stream>>>(
        xb, wqkvT, bqkvb, qkb, nullptr, vtb, (const u32*)d_in[0],
        SEQ, NQKV, DIM);
    attn_kernel<<<dim3(SEQ / 64, HEADS), 256, 0, stream>>>(qkb, vtb, attnb);
    gemm128<0><<<dim3(DIM / 128, SEQ / 128), 256, 0, stream>>>(
        attnb, wprojT, bprojb, (u16*)d_out, (float*)d_out, nullptr,
        (const u32*)d_in[0], SEQ, DIM, DIM);
}